// Round 5
// baseline (238.845 us; speedup 1.0000x reference)
//
#include <hip/hip_runtime.h>
#include <hip/hip_bf16.h>
#include <math.h>

#define TOKENS 16384
#define DIM    2048
#define NEXP   16

typedef float fvec4 __attribute__((ext_vector_type(4)));

// R5: W staged in LDS (fp32, two 64KB K-halves), x streamed from global.
// Wave = 32-lane k-split x 2 token-groups x 2 tokens/lane = 4 tokens/wave.
// Block 512 thr (8 waves) = 32 tokens; grid 512 -> 2 blocks/CU (64KB LDS each)
// = 16 waves/CU resident. Per jj-iter: 2 x-loads (VMEM) + 16 ds_read_b128
// (LGKM) + 128 FMAs -- W reads off the global path entirely.

__device__ __forceinline__ float fma4(fvec4 a, fvec4 w, float acc) {
    return fmaf(a.x, w.x, fmaf(a.y, w.y, fmaf(a.z, w.z, fmaf(a.w, w.w, acc))));
}

__global__ __launch_bounds__(512, 4) void gating_moe_kernel(
    const float* __restrict__ x,
    const float* __restrict__ noise,
    const float* __restrict__ W,
    const float* __restrict__ b,
    float* __restrict__ out)
{
    __shared__ fvec4 Wl[NEXP * 256];   // 64 KB: one K-half of W [16][256] fvec4

    const int tid    = threadIdx.x;
    const int lane   = tid & 63;
    const int waveI  = tid >> 6;         // 0..7
    const int sub    = lane & 31;        // k-split slot
    const int tgroup = lane >> 5;        // 0,1
    const int wave_base = blockIdx.x * 32 + waveI * 4;   // 4 tokens per wave
    const int t0 = wave_base + tgroup * 2;               // this lane's 2 tokens

    float acc[2][NEXP];
#pragma unroll
    for (int t = 0; t < 2; ++t)
#pragma unroll
        for (int e = 0; e < NEXP; ++e) acc[t][e] = 0.0f;

    const fvec4* __restrict__ xr = (const fvec4*)(x + (size_t)t0 * DIM); // 2 rows x 512
    const fvec4* __restrict__ Wg = (const fvec4*)W;                      // [16][512]

#pragma unroll
    for (int h = 0; h < 2; ++h) {
        if (h) __syncthreads();          // all waves done reading previous half
        // ---- stage K-half h of W into LDS (coalesced, 8 fvec4/thread) ----
#pragma unroll
        for (int t = 0; t < 8; ++t) {
            const int i = tid + t * 512;           // flat [16][256]
            const int e = i >> 8, c = i & 255;
            Wl[i] = Wg[e * 512 + h * 256 + c];
        }
        __syncthreads();

        // ---- main loop over this K-half ----
#pragma unroll
        for (int jj = 0; jj < 8; ++jj) {
            const int idx = jj * 32 + sub;
            fvec4 xv0 = xr[0 * 512 + h * 256 + idx];
            fvec4 xv1 = xr[1 * 512 + h * 256 + idx];

            fvec4 wv[8];
#pragma unroll
            for (int e = 0; e < 8; ++e) wv[e] = Wl[e * 256 + idx];
#pragma unroll
            for (int e = 0; e < 8; ++e) {
                acc[0][e] = fma4(xv0, wv[e], acc[0][e]);
                acc[1][e] = fma4(xv1, wv[e], acc[1][e]);
            }
#pragma unroll
            for (int e = 0; e < 8; ++e) wv[e] = Wl[(e + 8) * 256 + idx];
#pragma unroll
            for (int e = 0; e < 8; ++e) {
                acc[0][e + 8] = fma4(xv0, wv[e], acc[0][e + 8]);
                acc[1][e + 8] = fma4(xv1, wv[e], acc[1][e + 8]);
            }
        }
    }

    // ---- Reduce across the 32 k-split lanes (xor 1..16 stays within each
    // 32-lane half, so the two token-groups reduce independently). ----
#pragma unroll
    for (int t = 0; t < 2; ++t)
#pragma unroll
        for (int e = 0; e < NEXP; ++e) {
            float v = acc[t][e];
            v += __shfl_xor(v, 1);
            v += __shfl_xor(v, 2);
            v += __shfl_xor(v, 4);
            v += __shfl_xor(v, 8);
            v += __shfl_xor(v, 16);
            acc[t][e] = v;   // all 32 lanes of the half hold the full sum
        }

    // ---- Per-lane token select: 16 lanes per token.
    // token = wave_base + (lane>>4); local acc index = (lane>>4)&1.
    const int tsel  = (lane >> 4) & 1;
    const int token = wave_base + (lane >> 4);

    float full[NEXP];
#pragma unroll
    for (int e = 0; e < NEXP; ++e)
        full[e] = tsel ? acc[1][e] : acc[0][e];

    // ---- Epilogue: bias + 0.1*noise, top-2, softmax (redundant per 16 lanes).
    const fvec4* __restrict__ nz4 = (const fvec4*)(noise + (size_t)token * NEXP);
    float noisy[NEXP];
#pragma unroll
    for (int q = 0; q < 4; ++q) {
        fvec4 nv = nz4[q];
        noisy[q * 4 + 0] = full[q * 4 + 0] + b[q * 4 + 0] + 0.1f * nv.x;
        noisy[q * 4 + 1] = full[q * 4 + 1] + b[q * 4 + 1] + 0.1f * nv.y;
        noisy[q * 4 + 2] = full[q * 4 + 2] + b[q * 4 + 2] + 0.1f * nv.z;
        noisy[q * 4 + 3] = full[q * 4 + 3] + b[q * 4 + 3] + 0.1f * nv.w;
    }

    // Top-2, ties -> lowest index (matches jax.lax.top_k).
    float v1 = -INFINITY; int i1 = -1;
#pragma unroll
    for (int e = 0; e < NEXP; ++e) {
        bool g = noisy[e] > v1;
        v1 = g ? noisy[e] : v1;
        i1 = g ? e : i1;
    }
    float v2 = -INFINITY; int i2 = -1;
#pragma unroll
    for (int e = 0; e < NEXP; ++e) {
        bool g = (e != i1) && (noisy[e] > v2);
        v2 = g ? noisy[e] : v2;
        i2 = g ? e : i2;
    }

    float d  = __expf(v2 - v1);
    float w1 = 1.0f / (1.0f + d);
    float w2 = d * w1;

    // Lane writes ONE float: expert e = lane&15 of its token.
    // out idx = token*16 + e = wave_base*16 + lane -> 256B contiguous per wave.
    const int e = lane & 15;
    float o = (e == i1) ? w1 : ((e == i2) ? w2 : 0.0f);
    out[(size_t)wave_base * NEXP + lane] = o;
}

extern "C" void kernel_launch(void* const* d_in, const int* in_sizes, int n_in,
                              void* d_out, int out_size, void* d_ws, size_t ws_size,
                              hipStream_t stream) {
    const float* x     = (const float*)d_in[0];
    const float* noise = (const float*)d_in[1];
    const float* W     = (const float*)d_in[2];
    const float* b     = (const float*)d_in[3];
    float* out = (float*)d_out;

    dim3 grid(TOKENS / 32);   // 512 blocks
    dim3 block(512);
    gating_moe_kernel<<<grid, block, 0, stream>>>(x, noise, W, b, out);
}

// Round 6
// 195.251 us; speedup vs baseline: 1.2233x; 1.2233x over previous
//
#include <hip/hip_runtime.h>
#include <hip/hip_bf16.h>
#include <math.h>

#define TOKENS 16384
#define DIM    2048
#define NEXP   16
#define CHUNK  256                 // floats per K-chunk (1 KB per row)
#define NCHUNK (DIM / CHUNK)       // 8
#define TPB    16                  // tokens per block
#define NWAVE  4                   // waves per block (256 thr)

typedef float fvec4 __attribute__((ext_vector_type(4)));
typedef float f32_as1 __attribute__((address_space(1)));
typedef float f32_as3 __attribute__((address_space(3)));

// Async DMA: 64 lanes x 16 B -> LDS row (wave-uniform base + lane*16).
// gp is the PER-LANE global address (row_base + lane*16B); lp the LDS row base.
__device__ __forceinline__ void async_row(const float* gp, float* lp) {
    __builtin_amdgcn_global_load_lds((const f32_as1*)(const void*)gp,
                                     (f32_as3*)(uintptr_t)lp, 16, 0, 0);
}

// R6: m97-style async K-loop. Double-buffered LDS tiles for x (16 tok x 256)
// and W (16 exp x 256), staged with global_load_lds width=16 (no VGPR
// round-trip, deep fetch queue). Lane = 64-way k-split (4 floats/chunk);
// wave owns 4 tokens; acc r[64] = (t,e). End: 63-step butterfly
// reduce-scatter -> lane L holds logit(t=L>>4, e=L&15); 16-lane top-2 merge
// + softmax; coalesced store.
__global__ __launch_bounds__(256, 2) void gating_moe_kernel(
    const float* __restrict__ x,
    const float* __restrict__ noise,
    const float* __restrict__ W,
    const float* __restrict__ b,
    float* __restrict__ out)
{
    __shared__ __align__(16) float xb[2][TPB][CHUNK];   // 2 x 16 KB
    __shared__ __align__(16) float wb[2][NEXP][CHUNK];  // 2 x 16 KB

    const int tid  = threadIdx.x;
    const int lane = tid & 63;
    const int w    = tid >> 6;                   // wave 0..3
    const int block_base = blockIdx.x * TPB;     // first token of block
    const int lane4 = lane * 4;                  // float offset of lane's granule

    float r[64];
#pragma unroll
    for (int v = 0; v < 64; ++v) r[v] = 0.0f;

    // ---- prologue: stage chunk 0 into buffer 0 ----
    // wave w stages x rows w*4..w*4+3 and W experts w*4..w*4+3.
#pragma unroll
    for (int q = 0; q < 4; ++q) {
        const int row = w * 4 + q;
        async_row(x + (size_t)(block_base + row) * DIM + lane4, &xb[0][row][0]);
        async_row(W + (size_t)row * DIM + lane4, &wb[0][row][0]);
    }
    __syncthreads();   // compiler emits vmcnt(0) before barrier -> buf0 ready

    for (int c = 0; c < NCHUNK; ++c) {
        const int cur = c & 1, nxt = cur ^ 1;
        // ---- issue async staging of chunk c+1 (flies during compute) ----
        if (c + 1 < NCHUNK) {
#pragma unroll
            for (int q = 0; q < 4; ++q) {
                const int row = w * 4 + q;
                async_row(x + (size_t)(block_base + row) * DIM + (c + 1) * CHUNK + lane4,
                          &xb[nxt][row][0]);
                async_row(W + (size_t)row * DIM + (c + 1) * CHUNK + lane4,
                          &wb[nxt][row][0]);
            }
        }
        // ---- compute chunk c ----
        fvec4 xv[4];
#pragma unroll
        for (int t = 0; t < 4; ++t)
            xv[t] = *(const fvec4*)&xb[cur][w * 4 + t][lane4];
#pragma unroll
        for (int e = 0; e < NEXP; ++e) {
            fvec4 wv = *(const fvec4*)&wb[cur][e][lane4];
#pragma unroll
            for (int t = 0; t < 4; ++t) {
                r[t * 16 + e] = fmaf(xv[t].x, wv.x,
                               fmaf(xv[t].y, wv.y,
                               fmaf(xv[t].z, wv.z,
                               fmaf(xv[t].w, wv.w, r[t * 16 + e]))));
            }
        }
        __syncthreads();   // drains staging of c+1; guards buffer reuse
    }

    // ---- butterfly reduce-scatter over 64 lanes: after stage s, r[i]
    // corresponds to value v = (i << (s+1)) + (lane & ((2<<s)-1)).
    // Final: lane L holds the full sum for v = L = t*16 + e. ----
#pragma unroll
    for (int s = 0; s < 6; ++s) {
        const int dist = 1 << s;
        const bool bsel = (lane >> s) & 1;
        const int n = 64 >> (s + 1);
#pragma unroll
        for (int i = 0; i < n; ++i) {
            float keep = bsel ? r[2 * i + 1] : r[2 * i];
            float send = bsel ? r[2 * i]     : r[2 * i + 1];
            r[i] = keep + __shfl_xor(send, dist);
        }
    }

    // ---- epilogue: lane L -> (t = L>>4, e = L&15) of this wave ----
    const int e = lane & 15;
    const size_t obase = (size_t)block_base * NEXP + (size_t)w * 64;
    float nz   = noise[obase + lane];           // noise[t][e], coalesced
    float bias = b[e];
    float noisy = r[0] + bias + 0.1f * nz;

    // Top-2 across the 16 lanes of the token group (xor 1,2,4,8 stays inside).
    float v1 = noisy; int i1 = e;
    float v2 = -INFINITY; int i2 = 999;
#pragma unroll
    for (int s = 0; s < 4; ++s) {
        const int d = 1 << s;
        float ov1 = __shfl_xor(v1, d); int oi1 = __shfl_xor(i1, d);
        float ov2 = __shfl_xor(v2, d); int oi2 = __shfl_xor(i2, d);
        // merge sorted pairs; ties -> lowest index (matches jax.lax.top_k)
        bool awin = (v1 > ov1) || (v1 == ov1 && i1 < oi1);
        float t1v = awin ? v1  : ov1;  int t1i = awin ? i1  : oi1;
        float lv  = awin ? ov1 : v1;   int li  = awin ? oi1 : i1;
        float cv  = awin ? v2  : ov2;  int ci  = awin ? i2  : oi2;
        bool bwin = (cv > lv) || (cv == lv && ci < li);
        v1 = t1v; i1 = t1i;
        v2 = bwin ? cv : lv; i2 = bwin ? ci : li;
    }

    float dd = __expf(v2 - v1);
    float w1 = 1.0f / (1.0f + dd);
    float w2 = dd * w1;

    float o = (e == i1) ? w1 : ((e == i2) ? w2 : 0.0f);
    out[obase + lane] = o;   // out[t*16 + e], coalesced 256B per wave
}

extern "C" void kernel_launch(void* const* d_in, const int* in_sizes, int n_in,
                              void* d_out, int out_size, void* d_ws, size_t ws_size,
                              hipStream_t stream) {
    const float* x     = (const float*)d_in[0];
    const float* noise = (const float*)d_in[1];
    const float* W     = (const float*)d_in[2];
    const float* b     = (const float*)d_in[3];
    float* out = (float*)d_out;

    dim3 grid(TOKENS / TPB);   // 1024 blocks
    dim3 block(NWAVE * 64);    // 256 threads
    gating_moe_kernel<<<grid, block, 0, stream>>>(x, noise, W, b, out);
}

// Round 7
// 191.085 us; speedup vs baseline: 1.2499x; 1.0218x over previous
//
#include <hip/hip_runtime.h>
#include <hip/hip_bf16.h>
#include <math.h>

#define TOKENS 16384
#define DIM    2048
#define NEXP   16
#define CHUNK  256                 // floats per K-chunk (1 KB per row)
#define NCHUNK (DIM / CHUNK)       // 8
#define TPB    16                  // tokens per block
#define NWAVE  4                   // waves per block (256 thr)

typedef float fvec4 __attribute__((ext_vector_type(4)));
typedef float f32_as1 __attribute__((address_space(1)));
typedef float f32_as3 __attribute__((address_space(3)));

// Async DMA: 64 lanes x 16 B -> LDS row (wave-uniform base + lane*16).
// aux is the CPol bits: 0 = default (allocate), 2 = NT (non-temporal,
// no-allocate / evict-first) -- used for the zero-reuse x stream so it
// doesn't evict the harness's dirty ws-poison lines from L3 (whose
// writebacks were charged to our dispatch: WRITE_SIZE 61-143MB in R4/R5).
__device__ __forceinline__ void async_row_nt(const float* gp, float* lp) {
    __builtin_amdgcn_global_load_lds((const f32_as1*)(const void*)gp,
                                     (f32_as3*)(uintptr_t)lp, 16, 0, 2);
}
__device__ __forceinline__ void async_row(const float* gp, float* lp) {
    __builtin_amdgcn_global_load_lds((const f32_as1*)(const void*)gp,
                                     (f32_as3*)(uintptr_t)lp, 16, 0, 0);
}

// R7 = R6 + NT on x staging. Double-buffered LDS tiles for x (16 tok x 256)
// and W (16 exp x 256), staged with global_load_lds width=16. Lane = 64-way
// k-split (4 floats/chunk); wave owns 4 tokens; acc r[64] = (t,e). End:
// 6-stage butterfly reduce-scatter -> lane L holds logit(t=L>>4, e=L&15);
// 16-lane top-2 merge + softmax; coalesced store.
__global__ __launch_bounds__(256, 2) void gating_moe_kernel(
    const float* __restrict__ x,
    const float* __restrict__ noise,
    const float* __restrict__ W,
    const float* __restrict__ b,
    float* __restrict__ out)
{
    __shared__ __align__(16) float xb[2][TPB][CHUNK];   // 2 x 16 KB
    __shared__ __align__(16) float wb[2][NEXP][CHUNK];  // 2 x 16 KB

    const int tid  = threadIdx.x;
    const int lane = tid & 63;
    const int w    = tid >> 6;                   // wave 0..3
    const int block_base = blockIdx.x * TPB;     // first token of block
    const int lane4 = lane * 4;                  // float offset of lane's granule

    float r[64];
#pragma unroll
    for (int v = 0; v < 64; ++v) r[v] = 0.0f;

    // ---- prologue: stage chunk 0 into buffer 0 ----
    // wave w stages x rows w*4..w*4+3 and W experts w*4..w*4+3.
#pragma unroll
    for (int q = 0; q < 4; ++q) {
        const int row = w * 4 + q;
        async_row_nt(x + (size_t)(block_base + row) * DIM + lane4, &xb[0][row][0]);
        async_row(W + (size_t)row * DIM + lane4, &wb[0][row][0]);
    }
    __syncthreads();   // vmcnt(0) before barrier -> buf0 ready

    for (int c = 0; c < NCHUNK; ++c) {
        const int cur = c & 1, nxt = cur ^ 1;
        // ---- issue async staging of chunk c+1 (flies during compute) ----
        if (c + 1 < NCHUNK) {
#pragma unroll
            for (int q = 0; q < 4; ++q) {
                const int row = w * 4 + q;
                async_row_nt(x + (size_t)(block_base + row) * DIM + (c + 1) * CHUNK + lane4,
                             &xb[nxt][row][0]);
                async_row(W + (size_t)row * DIM + (c + 1) * CHUNK + lane4,
                          &wb[nxt][row][0]);
            }
        }
        // ---- compute chunk c ----
        fvec4 xv[4];
#pragma unroll
        for (int t = 0; t < 4; ++t)
            xv[t] = *(const fvec4*)&xb[cur][w * 4 + t][lane4];
#pragma unroll
        for (int e = 0; e < NEXP; ++e) {
            fvec4 wv = *(const fvec4*)&wb[cur][e][lane4];
#pragma unroll
            for (int t = 0; t < 4; ++t) {
                r[t * 16 + e] = fmaf(xv[t].x, wv.x,
                               fmaf(xv[t].y, wv.y,
                               fmaf(xv[t].z, wv.z,
                               fmaf(xv[t].w, wv.w, r[t * 16 + e]))));
            }
        }
        __syncthreads();   // drains staging of c+1; guards buffer reuse
    }

    // ---- butterfly reduce-scatter over 64 lanes: after stage s, r[i]
    // holds the partial for value v = (i << (s+1)) + (lane & ((2<<s)-1)).
    // Final: lane L holds the full sum for v = L = t*16 + e. ----
#pragma unroll
    for (int s = 0; s < 6; ++s) {
        const int dist = 1 << s;
        const bool bsel = (lane >> s) & 1;
        const int n = 64 >> (s + 1);
#pragma unroll
        for (int i = 0; i < n; ++i) {
            float keep = bsel ? r[2 * i + 1] : r[2 * i];
            float send = bsel ? r[2 * i]     : r[2 * i + 1];
            r[i] = keep + __shfl_xor(send, dist);
        }
    }

    // ---- epilogue: lane L -> (t = L>>4, e = L&15) of this wave ----
    const int e = lane & 15;
    const size_t obase = (size_t)block_base * NEXP + (size_t)w * 64;
    float nz   = noise[obase + lane];           // noise[t][e], coalesced
    float bias = b[e];
    float noisy = r[0] + bias + 0.1f * nz;

    // Top-2 across the 16 lanes of the token group (xor 1,2,4,8 stays inside).
    float v1 = noisy; int i1 = e;
    float v2 = -INFINITY; int i2 = 999;
#pragma unroll
    for (int s = 0; s < 4; ++s) {
        const int d = 1 << s;
        float ov1 = __shfl_xor(v1, d); int oi1 = __shfl_xor(i1, d);
        float ov2 = __shfl_xor(v2, d); int oi2 = __shfl_xor(i2, d);
        // merge sorted pairs; ties -> lowest index (matches jax.lax.top_k)
        bool awin = (v1 > ov1) || (v1 == ov1 && i1 < oi1);
        float t1v = awin ? v1  : ov1;  int t1i = awin ? i1  : oi1;
        float lv  = awin ? ov1 : v1;   int li  = awin ? oi1 : i1;
        float cv  = awin ? v2  : ov2;  int ci  = awin ? i2  : oi2;
        bool bwin = (cv > lv) || (cv == lv && ci < li);
        v1 = t1v; i1 = t1i;
        v2 = bwin ? cv : lv; i2 = bwin ? ci : li;
    }

    float dd = __expf(v2 - v1);
    float w1 = 1.0f / (1.0f + dd);
    float w2 = dd * w1;

    float o = (e == i1) ? w1 : ((e == i2) ? w2 : 0.0f);
    out[obase + lane] = o;   // out[t*16 + e], coalesced 256B per wave
}

extern "C" void kernel_launch(void* const* d_in, const int* in_sizes, int n_in,
                              void* d_out, int out_size, void* d_ws, size_t ws_size,
                              hipStream_t stream) {
    const float* x     = (const float*)d_in[0];
    const float* noise = (const float*)d_in[1];
    const float* W     = (const float*)d_in[2];
    const float* b     = (const float*)d_in[3];
    float* out = (float*)d_out;

    dim3 grid(TOKENS / TPB);   // 1024 blocks
    dim3 block(NWAVE * 64);    // 256 threads
    gating_moe_kernel<<<grid, block, 0, stream>>>(x, noise, W, b, out);
}

// Round 8
// 188.447 us; speedup vs baseline: 1.2674x; 1.0140x over previous
//
#include <hip/hip_runtime.h>
#include <hip/hip_bf16.h>
#include <math.h>

#define TOKENS 16384
#define DIM    2048
#define NEXP   16
#define CHUNK  256                 // K-floats per chunk (1 KB per row)
#define NCHUNK (DIM / CHUNK)       // 8
#define TPB    16                  // tokens per block
#define NWAVE  4                   // waves per block (256 thr)

typedef float fvec4 __attribute__((ext_vector_type(4)));
typedef float f32_as1 __attribute__((address_space(1)));
typedef float f32_as3 __attribute__((address_space(3)));

// Async DMA: 64 lanes x 16 B -> 1 KB LDS row (wave-uniform base + lane*16).
__device__ __forceinline__ void async_row(const float* gp, float* lp) {
    __builtin_amdgcn_global_load_lds((const f32_as1*)(const void*)gp,
                                     (f32_as3*)(uintptr_t)lp, 16, 0, 0);
}

// R8: split streams by destination.
//   x  (HBM, no reuse)  -> VGPR-dest nontemporal loads, 1-chunk prefetch.
//      Not LDS-dest => barrier doesn't structurally serialize its transfer.
//   W  (L2-resident)    -> 2x16KB LDS double-buffer via global_load_lds;
//      the per-chunk barrier only waits on this cheap L2 fetch.
// Wave = 64-lane k-split x 4 tokens; acc r[64]=(t,e); 4 blocks/CU.
// Epilogue: 6-stage butterfly reduce-scatter + 16-lane top-2 + softmax.
__global__ __launch_bounds__(256, 4) void gating_moe_kernel(
    const float* __restrict__ x,
    const float* __restrict__ noise,
    const float* __restrict__ W,
    const float* __restrict__ b,
    float* __restrict__ out)
{
    __shared__ __align__(16) fvec4 wbuf[2][NEXP][CHUNK / 4];  // 2 x 16 KB

    const int tid  = threadIdx.x;
    const int lane = tid & 63;
    const int w    = tid >> 6;                   // wave 0..3
    const int block_base = blockIdx.x * TPB;
    const int lane4 = lane * 4;                  // lane's float offset in chunk

    float r[64];
#pragma unroll
    for (int v = 0; v < 64; ++v) r[v] = 0.0f;

    // x row pointers for this wave's 4 tokens
    const float* xr0 = x + (size_t)(block_base + w * 4 + 0) * DIM + lane4;
    const float* xr1 = xr0 + DIM;
    const float* xr2 = xr1 + DIM;
    const float* xr3 = xr2 + DIM;

    // ---- prologue: stage W chunk 0; load x chunk 0 into regs ----
#pragma unroll
    for (int q = 0; q < 4; ++q) {
        const int e = w * 4 + q;
        async_row(W + (size_t)e * DIM + lane4, (float*)&wbuf[0][e][0]);
    }
    fvec4 xv0 = __builtin_nontemporal_load((const fvec4*)xr0);
    fvec4 xv1 = __builtin_nontemporal_load((const fvec4*)xr1);
    fvec4 xv2 = __builtin_nontemporal_load((const fvec4*)xr2);
    fvec4 xv3 = __builtin_nontemporal_load((const fvec4*)xr3);
    __syncthreads();

#pragma unroll
    for (int c = 0; c < NCHUNK; ++c) {
        const int cur = c & 1, nxt = cur ^ 1;
        fvec4 xn0, xn1, xn2, xn3;
        if (c + 1 < NCHUNK) {
            // stage W chunk c+1 (L2 hit) + prefetch x chunk c+1 to regs
#pragma unroll
            for (int q = 0; q < 4; ++q) {
                const int e = w * 4 + q;
                async_row(W + (size_t)e * DIM + (c + 1) * CHUNK + lane4,
                          (float*)&wbuf[nxt][e][0]);
            }
            const int off = (c + 1) * CHUNK;
            xn0 = __builtin_nontemporal_load((const fvec4*)(xr0 + off));
            xn1 = __builtin_nontemporal_load((const fvec4*)(xr1 + off));
            xn2 = __builtin_nontemporal_load((const fvec4*)(xr2 + off));
            xn3 = __builtin_nontemporal_load((const fvec4*)(xr3 + off));
        }

        // ---- compute chunk c: 16 experts x 4 tokens ----
#pragma unroll
        for (int eb = 0; eb < NEXP; eb += 2) {
            fvec4 wa = wbuf[cur][eb + 0][lane];
            fvec4 wc = wbuf[cur][eb + 1][lane];
#define FMA4(acc, xv, wv) acc = fmaf((xv).x,(wv).x, fmaf((xv).y,(wv).y, \
                                fmaf((xv).z,(wv).z, fmaf((xv).w,(wv).w,(acc)))))
            FMA4(r[0  * 16 + eb],     xv0, wa);
            FMA4(r[1  * 16 + eb],     xv1, wa);
            FMA4(r[2  * 16 + eb],     xv2, wa);
            FMA4(r[3  * 16 + eb],     xv3, wa);
            FMA4(r[0  * 16 + eb + 1], xv0, wc);
            FMA4(r[1  * 16 + eb + 1], xv1, wc);
            FMA4(r[2  * 16 + eb + 1], xv2, wc);
            FMA4(r[3  * 16 + eb + 1], xv3, wc);
#undef FMA4
        }
        __syncthreads();   // waits W staging of c+1 (L2-cheap); guards buffers
        if (c + 1 < NCHUNK) { xv0 = xn0; xv1 = xn1; xv2 = xn2; xv3 = xn3; }
    }

    // ---- butterfly reduce-scatter over 64 lanes: after stage s, r[i]
    // holds the partial for value v = (i << (s+1)) + (lane & ((2<<s)-1)).
    // Final: lane L holds the full sum for v = L = t*16 + e. ----
#pragma unroll
    for (int s = 0; s < 6; ++s) {
        const int dist = 1 << s;
        const bool bsel = (lane >> s) & 1;
        const int n = 64 >> (s + 1);
#pragma unroll
        for (int i = 0; i < n; ++i) {
            float keep = bsel ? r[2 * i + 1] : r[2 * i];
            float send = bsel ? r[2 * i]     : r[2 * i + 1];
            r[i] = keep + __shfl_xor(send, dist);
        }
    }

    // ---- epilogue: lane L -> (t = L>>4, e = L&15) of this wave ----
    const int e = lane & 15;
    const size_t obase = (size_t)block_base * NEXP + (size_t)w * 64;
    float nz    = noise[obase + lane];          // noise[t][e], coalesced
    float noisy = r[0] + b[e] + 0.1f * nz;

    // Top-2 across the 16 lanes of the token group (xor 1,2,4,8 stays inside).
    float v1 = noisy; int i1 = e;
    float v2 = -INFINITY; int i2 = 999;
#pragma unroll
    for (int s = 0; s < 4; ++s) {
        const int d = 1 << s;
        float ov1 = __shfl_xor(v1, d); int oi1 = __shfl_xor(i1, d);
        float ov2 = __shfl_xor(v2, d); int oi2 = __shfl_xor(i2, d);
        bool awin = (v1 > ov1) || (v1 == ov1 && i1 < oi1);
        float t1v = awin ? v1  : ov1;  int t1i = awin ? i1  : oi1;
        float lv  = awin ? ov1 : v1;   int li  = awin ? oi1 : i1;
        float cv  = awin ? v2  : ov2;  int ci  = awin ? i2  : oi2;
        bool bwin = (cv > lv) || (cv == lv && ci < li);
        v1 = t1v; i1 = t1i;
        v2 = bwin ? cv : lv; i2 = bwin ? ci : li;
    }

    float dd = __expf(v2 - v1);
    float w1 = 1.0f / (1.0f + dd);
    float w2 = dd * w1;

    float o = (e == i1) ? w1 : ((e == i2) ? w2 : 0.0f);
    out[obase + lane] = o;   // out[t*16 + e], 256B contiguous per wave
}

extern "C" void kernel_launch(void* const* d_in, const int* in_sizes, int n_in,
                              void* d_out, int out_size, void* d_ws, size_t ws_size,
                              hipStream_t stream) {
    const float* x     = (const float*)d_in[0];
    const float* noise = (const float*)d_in[1];
    const float* W     = (const float*)d_in[2];
    const float* b     = (const float*)d_in[3];
    float* out = (float*)d_out;

    dim3 grid(TOKENS / TPB);   // 1024 blocks
    dim3 block(NWAVE * 64);    // 256 threads
    gating_moe_kernel<<<grid, block, 0, stream>>>(x, noise, W, b, out);
}